// Round 3
// baseline (981.200 us; speedup 1.0000x reference)
//
#include <hip/hip_runtime.h>

// LightGCN: out = (e0 + A e0 + A^2 e0 + A^3 e0) / 4 over 150K nodes, 4.8M COO edges, D=64.
// R9: spmm gathers forced into flight via inline-asm global_load_ushort with
// double-buffered 16-edge banks and COUNTED s_waitcnt vmcnt(16) (T3/T4 pattern).
// R8's VGPR_Count=20 proved the compiler serialized the "16 independent gathers"
// to ~2-3 in flight (91 us vs ~20 us memory floor). asm volatile loads cannot be
// shrunk; vmcnt(16) retires only the oldest bank while the new bank's 16 loads stay
// outstanding. Scalar col/val streams read in the issue phase (SQC latency hidden
// under the in-flight bank). sched_barrier(0) after each wait (rule #18).
// launch_bounds(256,6): 85-VGPR cap, ~50 used -> no scratch spills (spills would
// corrupt the vmcnt count). Everything else (CSR build, padding, ws layout) = R8.

#define N_USERS 100000
#define N_ITEMS 50000
#define N_NODES 150000
#define N_EDGES 4800000
#define EMB_DIM 64

typedef unsigned short u16;
typedef unsigned int   u32;

constexpr int NODE_FLOATS  = N_NODES * EMB_DIM;      // 9,600,000
constexpr int NODE_FLOAT4S = NODE_FLOATS / 4;        // 2,400,000
constexpr int USER_FLOAT4S = N_USERS * EMB_DIM / 4;  // 1,600,000

constexpr int NB   = (N_NODES + 255) / 256;          // 586 buckets (256 rows each)
constexpr int NXG  = 8;                              // XCD groups (blockIdx & 7)
constexpr int SEG  = NB * NXG;                       // 4688 (bucket,x) segments
constexpr int CAP1 = 1280;                           // per-segment cap (mean 1024, +8 sigma)
constexpr int EPB  = 6144;                           // edges per stageA2 block
constexpr int ABLK2 = (N_EDGES + EPB - 1) / EPB;     // 782
constexpr int SB_CAP2 = 10880;                       // stageB2 LDS records, PADDED (mean 10112, +6.6 sigma)
constexpr int CSR_CAP = 6000000;                     // padded CSR entries (mean 5.925M, +42 sigma)

// ---- bf16 helpers (RNE) ----
static __device__ __forceinline__ float bf2f(u16 b) {
    return __uint_as_float(((u32)b) << 16);
}
static __device__ __forceinline__ u16 f2bf(float f) {
    u32 u = __float_as_uint(f);
    return (u16)((u + 0x7FFFu + ((u >> 16) & 1u)) >> 16);
}

// ---------------- init: buf0 = bf16(e0) ----------------
__global__ void init_kernel(const float* __restrict__ user_emb,
                            const float* __restrict__ item_emb,
                            u16* __restrict__ emb) {
    int i = blockIdx.x * blockDim.x + threadIdx.x;
    if (i >= NODE_FLOAT4S) return;
    float4 v = (i < USER_FLOAT4S) ? ((const float4*)user_emb)[i]
                                  : ((const float4*)item_emb)[i - USER_FLOAT4S];
    ushort4 o;
    o.x = f2bf(v.x); o.y = f2bf(v.y); o.z = f2bf(v.z); o.w = f2bf(v.w);
    ((ushort4*)emb)[i] = o;
}

// ---------------- init segment frontiers ----------------
__global__ void init_ptrs_kernel(int* __restrict__ bx_pos, int* __restrict__ csr_cursor) {
    int i = blockIdx.x * blockDim.x + threadIdx.x;
    if (i < SEG) bx_pos[i * 16] = i * CAP1;
    if (i == 0) csr_cursor[0] = 0;
}

// ---------------- stage A2: block-local counting sort by bucket ----------------
__global__ void stageA2_kernel(const int* __restrict__ rows,
                               const int* __restrict__ cols,
                               const float* __restrict__ vals,
                               int* __restrict__ bx_pos,
                               u32* __restrict__ stage_key,
                               u16* __restrict__ stage_val) {
    __shared__ u32 lkey[EPB];          // 24 KB
    __shared__ u16 lval[EPB];          // 12 KB
    __shared__ u16 lbkt[EPB];          // 12 KB
    __shared__ int hist[NB];
    __shared__ int hstart[NB];
    __shared__ int hcur[NB];
    __shared__ int gbase[NB];
    __shared__ int ws4[4];

    const int tid  = threadIdx.x;
    const int base = blockIdx.x * EPB;
    const int cnt  = min(EPB, N_EDGES - base);
    const int x    = blockIdx.x & (NXG - 1);

    for (int i = tid; i < NB; i += 256) hist[i] = 0;
    __syncthreads();

    for (int k = 0; k < EPB / 256; k += 8) {
        int rbuf[8];
        #pragma unroll
        for (int q = 0; q < 8; ++q) {
            int idx = (k + q) * 256 + tid;
            rbuf[q] = (idx < cnt) ? rows[base + idx] : -1;
        }
        #pragma unroll
        for (int q = 0; q < 8; ++q)
            if (rbuf[q] >= 0) atomicAdd(&hist[rbuf[q] >> 8], 1);
    }
    __syncthreads();

    const int lane = tid & 63, wave = tid >> 6;
    int carry = 0;
    for (int c0 = 0; c0 < NB; c0 += 256) {
        int i = c0 + tid;
        int v = (i < NB) ? hist[i] : 0;
        int incl = v;
        #pragma unroll
        for (int off = 1; off < 64; off <<= 1) {
            int t = __shfl_up(incl, off);
            if (lane >= off) incl += t;
        }
        if (lane == 63) ws4[wave] = incl;
        __syncthreads();
        int wpref = 0, tot = 0;
        #pragma unroll
        for (int w = 0; w < 4; ++w) { int s = ws4[w]; if (w < wave) wpref += s; tot += s; }
        int excl = carry + wpref + incl - v;
        if (i < NB) { hstart[i] = excl; hcur[i] = excl; }
        carry += tot;
        __syncthreads();
    }

    for (int k = 0; k < EPB / 256; k += 8) {
        int rb[8], cb[8]; float vb[8];
        #pragma unroll
        for (int q = 0; q < 8; ++q) {
            int idx = (k + q) * 256 + tid;
            if (idx < cnt) { rb[q] = rows[base + idx]; cb[q] = cols[base + idx]; vb[q] = vals[base + idx]; }
            else rb[q] = -1;
        }
        #pragma unroll
        for (int q = 0; q < 8; ++q) {
            if (rb[q] < 0) continue;
            int b = rb[q] >> 8;
            int p = atomicAdd(&hcur[b], 1);
            lkey[p] = ((u32)(rb[q] & 255) << 24) | (u32)cb[q];
            lval[p] = f2bf(vb[q]);
            lbkt[p] = (u16)b;
        }
    }
    __syncthreads();

    for (int i = tid; i < NB; i += 256) {
        int n = hist[i];
        if (n) {
            int seg = i * NXG + x;
            int p = atomicAdd(&bx_pos[seg * 16], n);
            gbase[i] = (p + n <= (seg + 1) * CAP1) ? p : -1;
        }
    }
    __syncthreads();

    for (int i = tid; i < cnt; i += 256) {
        int b  = lbkt[i];
        int gb = gbase[b];
        if (gb >= 0) {
            int d = gb + (i - hstart[b]);
            stage_key[d] = lkey[i];
            stage_val[d] = lval[i];
        }
    }
}

// -------- stage B2: per-bucket row sort in LDS, 16-PADDED contiguous CSR --------
__global__ void stageB2_kernel(const int* __restrict__ bx_pos,
                               const u32* __restrict__ stage_key,
                               const u16* __restrict__ stage_val,
                               int* __restrict__ csr_cursor,
                               u32* __restrict__ csr_col,
                               u16* __restrict__ csr_val,
                               u32* __restrict__ desc) {
    __shared__ u32 skey[SB_CAP2];      // 43.5 KB (col only)
    __shared__ u16 sval[SB_CAP2];      // 21.8 KB
    __shared__ int rhist[256], rpad0[256], rcur[256];
    __shared__ int ws4[4];
    __shared__ int sbase_sh;

    const int b   = blockIdx.x;
    const int tid = threadIdx.x;
    rhist[tid] = 0;
    __syncthreads();

    for (int xx = 0; xx < NXG; ++xx) {
        int seg = b * NXG + xx;
        int sb  = seg * CAP1;
        int n   = min(bx_pos[seg * 16] - sb, CAP1);
        for (int i = tid; i < n; i += 256)
            atomicAdd(&rhist[stage_key[sb + i] >> 24], 1);
    }
    __syncthreads();

    const int lane = tid & 63, wave = tid >> 6;
    int v  = rhist[tid];
    int vp = (v + 15) & ~15;           // padded count
    int incl = vp;
    #pragma unroll
    for (int off = 1; off < 64; off <<= 1) {
        int t = __shfl_up(incl, off);
        if (lane >= off) incl += t;
    }
    if (lane == 63) ws4[wave] = incl;
    __syncthreads();
    int wpref = 0, total = 0;
    #pragma unroll
    for (int w = 0; w < 4; ++w) { int s = ws4[w]; if (w < wave) wpref += s; total += s; }
    int excl = wpref + incl - vp;
    rpad0[tid] = excl;
    rcur[tid]  = excl;
    if (tid == 0) sbase_sh = atomicAdd(csr_cursor, total);
    __syncthreads();

    const int tcap = min(total, SB_CAP2);
    // pre-fill with dummies (col 0, val 0) -> padded slots contribute 0 in spmm
    for (int i = tid; i < tcap; i += 256) { skey[i] = 0u; sval[i] = 0; }
    __syncthreads();

    for (int xx = 0; xx < NXG; ++xx) {
        int seg = b * NXG + xx;
        int sb  = seg * CAP1;
        int n   = min(bx_pos[seg * 16] - sb, CAP1);
        for (int i = tid; i < n; i += 256) {
            u32 key = stage_key[sb + i];
            u16 val = stage_val[sb + i];
            int p = atomicAdd(&rcur[key >> 24], 1);
            if (p < SB_CAP2) { skey[p] = key & 0x00FFFFFFu; sval[p] = val; }
        }
    }
    __syncthreads();

    const int sbase = sbase_sh;
    for (int i = tid; i < tcap; i += 256) {
        int g = sbase + i;
        if (g < CSR_CAP) { csr_col[g] = skey[i]; csr_val[g] = sval[i]; }
    }
    int grow = b * 256 + tid;
    if (grow < N_NODES) {
        int cp = vp; if (cp > 240) cp = 240;
        desc[grow] = ((u32)(sbase + rpad0[tid]) << 8) | (u32)cp;
    }
}

// ------- CSR SpMM: ONE ROW PER WAVE, asm gathers, double-buffer, counted vmcnt -------
// Bank = 16 edges: 16x global_load_ushort (each = 64 lanes x 2B = one 128B line).
// While bank B's loads are in flight, vmcnt(16) retires bank A -> FMA A.
// Scalar col/val streams (s_load, lgkmcnt) read in the issue phase.
// layers 1/2: y = A x (bf16). layer 3 (y==null): out = (e0 + y1 + y2 + A x)/4 fp32.

static __device__ __forceinline__ void issue16(u32 (&bx)[16], u32 (&bw)[8],
                                               const u32* __restrict__ pc,
                                               const u32* __restrict__ pv,
                                               int ch, u32 lane2,
                                               const u16* __restrict__ x) {
    #pragma unroll
    for (int k = 0; k < 8; ++k) bw[k] = pv[ch * 8 + k];         // scalar val stream
    #pragma unroll
    for (int k = 0; k < 16; ++k) {
        u32 off = (pc[ch * 16 + k] << 7) + lane2;               // c*128 + lane*2
        asm volatile("global_load_ushort %0, %1, %2"
                     : "=v"(bx[k])
                     : "v"(off), "s"(x)
                     : "memory");
    }
}

static __device__ __forceinline__ void fma16(const u32 (&bx)[16], const u32 (&bw)[8],
                                             float (&a)[4]) {
    #pragma unroll
    for (int k = 0; k < 16; ++k) {
        u32 w  = bw[k >> 1];
        u32 vb = (k & 1) ? (w & 0xFFFF0000u) : (w << 16);
        a[k & 3] += __uint_as_float(vb) * __uint_as_float(bx[k] << 16);
    }
}

#define SPMM_WAIT_PIPE  { asm volatile("s_waitcnt vmcnt(16)" ::: "memory"); \
                          __builtin_amdgcn_sched_barrier(0); }
#define SPMM_WAIT_ALL   { asm volatile("s_waitcnt vmcnt(0)" ::: "memory");  \
                          __builtin_amdgcn_sched_barrier(0); }

__global__ __launch_bounds__(256, 6)
void spmm_rw_kernel(const u32* __restrict__ desc,
                    const u32* __restrict__ csr_col,
                    const u16* __restrict__ csr_val,
                    const u16* __restrict__ x,
                    u16* __restrict__ y,
                    const u16* __restrict__ e0,
                    const u16* __restrict__ y1,
                    const u16* __restrict__ y2,
                    float* __restrict__ out) {
    const int lane = threadIdx.x & 63;
    const u32 lane2 = (u32)lane * 2u;
    const int wid  = __builtin_amdgcn_readfirstlane(threadIdx.x >> 6);
    const int row  = blockIdx.x * 4 + wid;
    if (row >= N_NODES) return;

    const u32 d   = desc[row];
    const int beg = __builtin_amdgcn_readfirstlane((int)(d >> 8));
    const int nch = __builtin_amdgcn_readfirstlane((int)(d & 255u) >> 4);

    const u32* __restrict__ pc = csr_col + beg;
    const u32* __restrict__ pv = ((const u32*)csr_val) + (beg >> 1);  // beg even (16-aligned)

    float a[4] = {0.f, 0.f, 0.f, 0.f};
    u32 Ax[16], Aw[8], Bx[16], Bw[8];

    if (nch > 0) {
        issue16(Ax, Aw, pc, pv, 0, lane2, x);
        int ch = 0;
        for (;;) {
            if (ch + 1 < nch) { issue16(Bx, Bw, pc, pv, ch + 1, lane2, x); SPMM_WAIT_PIPE; }
            else              { SPMM_WAIT_ALL; }
            fma16(Ax, Aw, a);
            if (++ch >= nch) break;
            if (ch + 1 < nch) { issue16(Ax, Aw, pc, pv, ch + 1, lane2, x); SPMM_WAIT_PIPE; }
            else              { SPMM_WAIT_ALL; }
            fma16(Bx, Bw, a);
            if (++ch >= nch) break;
        }
    }
    float s = (a[0] + a[1]) + (a[2] + a[3]);

    size_t oidx = (size_t)row * EMB_DIM + lane;
    if (y) {
        y[oidx] = f2bf(s);
    } else {
        float r = (bf2f(e0[oidx]) + bf2f(y1[oidx]) + bf2f(y2[oidx]) + s) * 0.25f;
        out[oidx] = r;
    }
}

// ---------------- fallback (R0 atomic path) ----------------
__global__ void init3_kernel(const float* __restrict__ user_emb,
                             const float* __restrict__ item_emb,
                             float* __restrict__ emb,
                             float* __restrict__ acc,
                             float* __restrict__ nxt) {
    int i = blockIdx.x * blockDim.x + threadIdx.x;
    if (i >= NODE_FLOAT4S) return;
    float4 v = (i < USER_FLOAT4S) ? ((const float4*)user_emb)[i]
                                  : ((const float4*)item_emb)[i - USER_FLOAT4S];
    ((float4*)emb)[i] = v;
    ((float4*)acc)[i] = v;
    ((float4*)nxt)[i] = make_float4(0.f, 0.f, 0.f, 0.f);
}

__global__ void spmm_atomic_kernel(const int* __restrict__ rows,
                                   const int* __restrict__ cols,
                                   const float* __restrict__ vals,
                                   const float* __restrict__ x,
                                   float* __restrict__ y) {
    unsigned tid = blockIdx.x * blockDim.x + threadIdx.x;
    unsigned e  = tid >> 4;
    unsigned d4 = tid & 15u;
    if (e >= N_EDGES) return;
    int r = rows[e]; int c = cols[e]; float v = vals[e];
    float4 xv = ((const float4*)(x + (size_t)c * EMB_DIM))[d4];
    float* yp = y + (size_t)r * EMB_DIM + d4 * 4;
    atomicAdd(yp + 0, v * xv.x);
    atomicAdd(yp + 1, v * xv.y);
    atomicAdd(yp + 2, v * xv.z);
    atomicAdd(yp + 3, v * xv.w);
}

__global__ void acc_kernel(float* __restrict__ acc, const float* __restrict__ nxt,
                           float* __restrict__ zbuf, int do_zero, float scale) {
    int i = blockIdx.x * blockDim.x + threadIdx.x;
    if (i >= NODE_FLOAT4S) return;
    float4 a = ((float4*)acc)[i];
    float4 n = ((const float4*)nxt)[i];
    a.x = (a.x + n.x) * scale; a.y = (a.y + n.y) * scale;
    a.z = (a.z + n.z) * scale; a.w = (a.w + n.w) * scale;
    ((float4*)acc)[i] = a;
    if (do_zero) ((float4*)zbuf)[i] = make_float4(0.f, 0.f, 0.f, 0.f);
}

extern "C" void kernel_launch(void* const* d_in, const int* in_sizes, int n_in,
                              void* d_out, int out_size, void* d_ws, size_t ws_size,
                              hipStream_t stream) {
    const int*   rows     = (const int*)d_in[0];
    const int*   cols     = (const int*)d_in[1];
    const float* vals     = (const float*)d_in[2];
    const float* user_emb = (const float*)d_in[3];
    const float* item_emb = (const float*)d_in[4];
    float* out = (float*)d_out;

    // ws layout (u32 units):
    //   buf0 bf16 [4.8M]
    //   | STAGE region [9.6M]: stage_key [6.00064M] + stage_val u16 [3.00032M u32]
    //       (after stageB2 the region is dead; buf1 = [0..4.8M), buf2 = [4.8M..9.6M))
    //   | csr_col [6.0M padded] | csr_val u16 [3.0M u32] | desc [150K]
    //   | bx_pos [4688*16] | csr_cursor [16]
    constexpr size_t U_BUF   = (size_t)NODE_FLOATS / 2;   // 4,800,000
    constexpr size_t U_SKEY  = (size_t)SEG * CAP1;        // 6,000,640
    constexpr size_t U_STAGE = 2 * U_BUF;                 // 9,600,000 (>= U_SKEY+U_SVAL)
    constexpr size_t U_CCOL  = (size_t)CSR_CAP;           // 6,000,000
    constexpr size_t U_CVAL  = (size_t)CSR_CAP / 2;       // 3,000,000
    size_t need_u32 = U_BUF + U_STAGE + U_CCOL + U_CVAL + (size_t)N_NODES
                    + (size_t)SEG * 16 + 16;

    const int EW_BLOCKS = (NODE_FLOAT4S + 255) / 256;

    if (ws_size >= need_u32 * 4) {
        u32* W = (u32*)d_ws;
        u16* buf0      = (u16*)W;
        u32* stage_key = W + U_BUF;
        u16* stage_val = (u16*)(W + U_BUF + U_SKEY);
        u16* buf1      = (u16*)(W + U_BUF);               // alias: stage [0..4.8M)
        u16* buf2      = (u16*)(W + U_BUF + U_BUF);       // alias: stage [4.8M..9.6M)
        u32* csr_col   = W + U_BUF + U_STAGE;
        u16* csr_val   = (u16*)(csr_col + U_CCOL);
        u32* desc      = (u32*)(csr_col + U_CCOL + U_CVAL);
        int* bx_pos    = (int*)(desc + N_NODES);
        int* csr_cur   = bx_pos + (size_t)SEG * 16;

        init_ptrs_kernel<<<(SEG + 255) / 256, 256, 0, stream>>>(bx_pos, csr_cur);
        init_kernel<<<EW_BLOCKS, 256, 0, stream>>>(user_emb, item_emb, buf0);
        stageA2_kernel<<<ABLK2, 256, 0, stream>>>(rows, cols, vals, bx_pos,
                                                  stage_key, stage_val);
        stageB2_kernel<<<NB, 256, 0, stream>>>(bx_pos, stage_key, stage_val,
                                               csr_cur, csr_col, csr_val, desc);

        const int SPMM_BLOCKS = (N_NODES + 3) / 4;        // 4 rows (waves) per block
        spmm_rw_kernel<<<SPMM_BLOCKS, 256, 0, stream>>>(desc, csr_col, csr_val,
                                                        buf0, buf1, nullptr, nullptr, nullptr, nullptr);
        spmm_rw_kernel<<<SPMM_BLOCKS, 256, 0, stream>>>(desc, csr_col, csr_val,
                                                        buf1, buf2, nullptr, nullptr, nullptr, nullptr);
        spmm_rw_kernel<<<SPMM_BLOCKS, 256, 0, stream>>>(desc, csr_col, csr_val,
                                                        buf2, nullptr, buf0, buf1, buf2, out);
    } else {
        // fallback: R0 atomic path
        float* buf0 = (float*)d_ws;
        float* buf1 = buf0 + NODE_FLOATS;
        const int SPMM_BLOCKS = (int)(((size_t)N_EDGES * 16 + 255) / 256);
        init3_kernel<<<EW_BLOCKS, 256, 0, stream>>>(user_emb, item_emb, buf0, out, buf1);
        float* prev = buf0; float* next = buf1;
        for (int layer = 0; layer < 3; ++layer) {
            spmm_atomic_kernel<<<SPMM_BLOCKS, 256, 0, stream>>>(rows, cols, vals, prev, next);
            if (layer < 2) acc_kernel<<<EW_BLOCKS, 256, 0, stream>>>(out, next, prev, 1, 1.0f);
            else           acc_kernel<<<EW_BLOCKS, 256, 0, stream>>>(out, next, prev, 0, 0.25f);
            float* t = prev; prev = next; next = t;
        }
    }
}

// Round 4
// 498.871 us; speedup vs baseline: 1.9668x; 1.9668x over previous
//
#include <hip/hip_runtime.h>

// LightGCN: out = (e0 + A e0 + A^2 e0 + A^3 e0) / 4 over 150K nodes, 4.8M COO edges, D=64.
// R10: spmm MLP via SOURCE-LEVEL software pipelining, zero inline asm.
// R9's per-load asm volatile ("memory" clobber x16) made the waitcnt pass drain
// around every load -> 258us. R10 double-buffers the 16-gather bank in plain HIP:
// issue bank B (chunk j+1) loads, then FMA bank A (chunk j). The SSA structure
// forces compiler-generated COUNTED waits (vmcnt(31)->vmcnt(16) progressive) --
// T4 semantics, correct by construction. sched_barrier(0) pins issue order only.
// launch_bounds(256,6): 85-VGPR cap gives room for 32 live gather dests (R8's
// 8-wave/EU target made the scheduler shrink to ~2.5 in flight, VGPR=20).
// Everything else (CSR build, 16-padding, ws layout) = R8/R9.

#define N_USERS 100000
#define N_ITEMS 50000
#define N_NODES 150000
#define N_EDGES 4800000
#define EMB_DIM 64

typedef unsigned short u16;
typedef unsigned int   u32;

constexpr int NODE_FLOATS  = N_NODES * EMB_DIM;      // 9,600,000
constexpr int NODE_FLOAT4S = NODE_FLOATS / 4;        // 2,400,000
constexpr int USER_FLOAT4S = N_USERS * EMB_DIM / 4;  // 1,600,000

constexpr int NB   = (N_NODES + 255) / 256;          // 586 buckets (256 rows each)
constexpr int NXG  = 8;                              // XCD groups (blockIdx & 7)
constexpr int SEG  = NB * NXG;                       // 4688 (bucket,x) segments
constexpr int CAP1 = 1280;                           // per-segment cap (mean 1024, +8 sigma)
constexpr int EPB  = 6144;                           // edges per stageA2 block
constexpr int ABLK2 = (N_EDGES + EPB - 1) / EPB;     // 782
constexpr int SB_CAP2 = 10880;                       // stageB2 LDS records, PADDED (mean 10112, +6.6 sigma)
constexpr int CSR_CAP = 6000000;                     // padded CSR entries (mean 5.925M, +42 sigma)

// ---- bf16 helpers (RNE) ----
static __device__ __forceinline__ float bf2f(u16 b) {
    return __uint_as_float(((u32)b) << 16);
}
static __device__ __forceinline__ u16 f2bf(float f) {
    u32 u = __float_as_uint(f);
    return (u16)((u + 0x7FFFu + ((u >> 16) & 1u)) >> 16);
}

// ---------------- init: buf0 = bf16(e0) ----------------
__global__ void init_kernel(const float* __restrict__ user_emb,
                            const float* __restrict__ item_emb,
                            u16* __restrict__ emb) {
    int i = blockIdx.x * blockDim.x + threadIdx.x;
    if (i >= NODE_FLOAT4S) return;
    float4 v = (i < USER_FLOAT4S) ? ((const float4*)user_emb)[i]
                                  : ((const float4*)item_emb)[i - USER_FLOAT4S];
    ushort4 o;
    o.x = f2bf(v.x); o.y = f2bf(v.y); o.z = f2bf(v.z); o.w = f2bf(v.w);
    ((ushort4*)emb)[i] = o;
}

// ---------------- init segment frontiers ----------------
__global__ void init_ptrs_kernel(int* __restrict__ bx_pos, int* __restrict__ csr_cursor) {
    int i = blockIdx.x * blockDim.x + threadIdx.x;
    if (i < SEG) bx_pos[i * 16] = i * CAP1;
    if (i == 0) csr_cursor[0] = 0;
}

// ---------------- stage A2: block-local counting sort by bucket ----------------
__global__ void stageA2_kernel(const int* __restrict__ rows,
                               const int* __restrict__ cols,
                               const float* __restrict__ vals,
                               int* __restrict__ bx_pos,
                               u32* __restrict__ stage_key,
                               u16* __restrict__ stage_val) {
    __shared__ u32 lkey[EPB];          // 24 KB
    __shared__ u16 lval[EPB];          // 12 KB
    __shared__ u16 lbkt[EPB];          // 12 KB
    __shared__ int hist[NB];
    __shared__ int hstart[NB];
    __shared__ int hcur[NB];
    __shared__ int gbase[NB];
    __shared__ int ws4[4];

    const int tid  = threadIdx.x;
    const int base = blockIdx.x * EPB;
    const int cnt  = min(EPB, N_EDGES - base);
    const int x    = blockIdx.x & (NXG - 1);

    for (int i = tid; i < NB; i += 256) hist[i] = 0;
    __syncthreads();

    for (int k = 0; k < EPB / 256; k += 8) {
        int rbuf[8];
        #pragma unroll
        for (int q = 0; q < 8; ++q) {
            int idx = (k + q) * 256 + tid;
            rbuf[q] = (idx < cnt) ? rows[base + idx] : -1;
        }
        #pragma unroll
        for (int q = 0; q < 8; ++q)
            if (rbuf[q] >= 0) atomicAdd(&hist[rbuf[q] >> 8], 1);
    }
    __syncthreads();

    const int lane = tid & 63, wave = tid >> 6;
    int carry = 0;
    for (int c0 = 0; c0 < NB; c0 += 256) {
        int i = c0 + tid;
        int v = (i < NB) ? hist[i] : 0;
        int incl = v;
        #pragma unroll
        for (int off = 1; off < 64; off <<= 1) {
            int t = __shfl_up(incl, off);
            if (lane >= off) incl += t;
        }
        if (lane == 63) ws4[wave] = incl;
        __syncthreads();
        int wpref = 0, tot = 0;
        #pragma unroll
        for (int w = 0; w < 4; ++w) { int s = ws4[w]; if (w < wave) wpref += s; tot += s; }
        int excl = carry + wpref + incl - v;
        if (i < NB) { hstart[i] = excl; hcur[i] = excl; }
        carry += tot;
        __syncthreads();
    }

    for (int k = 0; k < EPB / 256; k += 8) {
        int rb[8], cb[8]; float vb[8];
        #pragma unroll
        for (int q = 0; q < 8; ++q) {
            int idx = (k + q) * 256 + tid;
            if (idx < cnt) { rb[q] = rows[base + idx]; cb[q] = cols[base + idx]; vb[q] = vals[base + idx]; }
            else rb[q] = -1;
        }
        #pragma unroll
        for (int q = 0; q < 8; ++q) {
            if (rb[q] < 0) continue;
            int b = rb[q] >> 8;
            int p = atomicAdd(&hcur[b], 1);
            lkey[p] = ((u32)(rb[q] & 255) << 24) | (u32)cb[q];
            lval[p] = f2bf(vb[q]);
            lbkt[p] = (u16)b;
        }
    }
    __syncthreads();

    for (int i = tid; i < NB; i += 256) {
        int n = hist[i];
        if (n) {
            int seg = i * NXG + x;
            int p = atomicAdd(&bx_pos[seg * 16], n);
            gbase[i] = (p + n <= (seg + 1) * CAP1) ? p : -1;
        }
    }
    __syncthreads();

    for (int i = tid; i < cnt; i += 256) {
        int b  = lbkt[i];
        int gb = gbase[b];
        if (gb >= 0) {
            int d = gb + (i - hstart[b]);
            stage_key[d] = lkey[i];
            stage_val[d] = lval[i];
        }
    }
}

// -------- stage B2: per-bucket row sort in LDS, 16-PADDED contiguous CSR --------
__global__ void stageB2_kernel(const int* __restrict__ bx_pos,
                               const u32* __restrict__ stage_key,
                               const u16* __restrict__ stage_val,
                               int* __restrict__ csr_cursor,
                               u32* __restrict__ csr_col,
                               u16* __restrict__ csr_val,
                               u32* __restrict__ desc) {
    __shared__ u32 skey[SB_CAP2];      // 43.5 KB (col only)
    __shared__ u16 sval[SB_CAP2];      // 21.8 KB
    __shared__ int rhist[256], rpad0[256], rcur[256];
    __shared__ int ws4[4];
    __shared__ int sbase_sh;

    const int b   = blockIdx.x;
    const int tid = threadIdx.x;
    rhist[tid] = 0;
    __syncthreads();

    for (int xx = 0; xx < NXG; ++xx) {
        int seg = b * NXG + xx;
        int sb  = seg * CAP1;
        int n   = min(bx_pos[seg * 16] - sb, CAP1);
        for (int i = tid; i < n; i += 256)
            atomicAdd(&rhist[stage_key[sb + i] >> 24], 1);
    }
    __syncthreads();

    const int lane = tid & 63, wave = tid >> 6;
    int v  = rhist[tid];
    int vp = (v + 15) & ~15;           // padded count
    int incl = vp;
    #pragma unroll
    for (int off = 1; off < 64; off <<= 1) {
        int t = __shfl_up(incl, off);
        if (lane >= off) incl += t;
    }
    if (lane == 63) ws4[wave] = incl;
    __syncthreads();
    int wpref = 0, total = 0;
    #pragma unroll
    for (int w = 0; w < 4; ++w) { int s = ws4[w]; if (w < wave) wpref += s; total += s; }
    int excl = wpref + incl - vp;
    rpad0[tid] = excl;
    rcur[tid]  = excl;
    if (tid == 0) sbase_sh = atomicAdd(csr_cursor, total);
    __syncthreads();

    const int tcap = min(total, SB_CAP2);
    // pre-fill with dummies (col 0, val 0) -> padded slots contribute 0 in spmm
    for (int i = tid; i < tcap; i += 256) { skey[i] = 0u; sval[i] = 0; }
    __syncthreads();

    for (int xx = 0; xx < NXG; ++xx) {
        int seg = b * NXG + xx;
        int sb  = seg * CAP1;
        int n   = min(bx_pos[seg * 16] - sb, CAP1);
        for (int i = tid; i < n; i += 256) {
            u32 key = stage_key[sb + i];
            u16 val = stage_val[sb + i];
            int p = atomicAdd(&rcur[key >> 24], 1);
            if (p < SB_CAP2) { skey[p] = key & 0x00FFFFFFu; sval[p] = val; }
        }
    }
    __syncthreads();

    const int sbase = sbase_sh;
    for (int i = tid; i < tcap; i += 256) {
        int g = sbase + i;
        if (g < CSR_CAP) { csr_col[g] = skey[i]; csr_val[g] = sval[i]; }
    }
    int grow = b * 256 + tid;
    if (grow < N_NODES) {
        int cp = vp; if (cp > 240) cp = 240;
        desc[grow] = ((u32)(sbase + rpad0[tid]) << 8) | (u32)cp;
    }
}

// ------- CSR SpMM: ONE ROW PER WAVE, plain-HIP double-buffered gather banks -------
// Bank = 16 edges (16 x global_load_ushort; each = 64 lanes x 2B = one 128B line).
// Bank B's loads are issued BEFORE bank A's FMAs consume xA -> the waitcnt pass
// emits counted vmcnt(31..16) automatically (in-order VMEM retirement). No asm
// loads, no manual waitcnt; sched_barrier(0) only pins issue order.
// layers 1/2: y = A x (bf16). layer 3 (y==null): out = (e0 + y1 + y2 + A x)/4 fp32.
__global__ __launch_bounds__(256, 6)
void spmm_rw_kernel(const u32* __restrict__ desc,
                    const u32* __restrict__ csr_col,
                    const u16* __restrict__ csr_val,
                    const u16* __restrict__ x,
                    u16* __restrict__ y,
                    const u16* __restrict__ e0,
                    const u16* __restrict__ y1,
                    const u16* __restrict__ y2,
                    float* __restrict__ out) {
    const int lane = threadIdx.x & 63;
    const int wid  = __builtin_amdgcn_readfirstlane(threadIdx.x >> 6);
    const int row  = blockIdx.x * 4 + wid;
    if (row >= N_NODES) return;

    const u32 d   = desc[row];
    const int beg = __builtin_amdgcn_readfirstlane((int)(d >> 8));
    const int nch = __builtin_amdgcn_readfirstlane((int)(d & 255u) >> 4);

    const u32* __restrict__ pc = csr_col + beg;
    const u32* __restrict__ pv = ((const u32*)csr_val) + (beg >> 1);  // beg even (16-aligned)
    const u16* __restrict__ xl = x + lane;

    float a[4] = {0.f, 0.f, 0.f, 0.f};
    u32 cA[16], cB[16], wA[8], wB[8], xA[16], xB[16];

    if (nch > 0) {
        // prologue: bank A <- chunk 0
        #pragma unroll
        for (int k = 0; k < 16; ++k) cA[k] = pc[k];            // scalar stream
        #pragma unroll
        for (int k = 0; k < 8; ++k)  wA[k] = pv[k];            // scalar bf16 vals x2
        #pragma unroll
        for (int k = 0; k < 16; ++k)
            xA[k] = (u32)xl[(size_t)cA[k] * EMB_DIM];          // 16 gathers in flight

        int ch = 0;
        for (;;) {
            // issue bank B (chunk ch+1) while bank A is in flight
            if (ch + 1 < nch) {
                #pragma unroll
                for (int k = 0; k < 16; ++k) cB[k] = pc[(ch + 1) * 16 + k];
                #pragma unroll
                for (int k = 0; k < 8; ++k)  wB[k] = pv[(ch + 1) * 8 + k];
                #pragma unroll
                for (int k = 0; k < 16; ++k)
                    xB[k] = (u32)xl[(size_t)cB[k] * EMB_DIM];
            }
            __builtin_amdgcn_sched_barrier(0);
            #pragma unroll
            for (int k = 0; k < 16; ++k) {                     // consume bank A
                u32 w  = wA[k >> 1];
                u32 vb = (k & 1) ? (w & 0xFFFF0000u) : (w << 16);
                a[k & 3] += __uint_as_float(vb) * __uint_as_float(xA[k] << 16);
            }
            if (++ch >= nch) break;

            // issue bank A (chunk ch+1) while bank B is in flight
            if (ch + 1 < nch) {
                #pragma unroll
                for (int k = 0; k < 16; ++k) cA[k] = pc[(ch + 1) * 16 + k];
                #pragma unroll
                for (int k = 0; k < 8; ++k)  wA[k] = pv[(ch + 1) * 8 + k];
                #pragma unroll
                for (int k = 0; k < 16; ++k)
                    xA[k] = (u32)xl[(size_t)cA[k] * EMB_DIM];
            }
            __builtin_amdgcn_sched_barrier(0);
            #pragma unroll
            for (int k = 0; k < 16; ++k) {                     // consume bank B
                u32 w  = wB[k >> 1];
                u32 vb = (k & 1) ? (w & 0xFFFF0000u) : (w << 16);
                a[k & 3] += __uint_as_float(vb) * __uint_as_float(xB[k] << 16);
            }
            if (++ch >= nch) break;
        }
    }
    float s = (a[0] + a[1]) + (a[2] + a[3]);

    size_t oidx = (size_t)row * EMB_DIM + lane;
    if (y) {
        y[oidx] = f2bf(s);
    } else {
        float r = (bf2f(e0[oidx]) + bf2f(y1[oidx]) + bf2f(y2[oidx]) + s) * 0.25f;
        out[oidx] = r;
    }
}

// ---------------- fallback (R0 atomic path) ----------------
__global__ void init3_kernel(const float* __restrict__ user_emb,
                             const float* __restrict__ item_emb,
                             float* __restrict__ emb,
                             float* __restrict__ acc,
                             float* __restrict__ nxt) {
    int i = blockIdx.x * blockDim.x + threadIdx.x;
    if (i >= NODE_FLOAT4S) return;
    float4 v = (i < USER_FLOAT4S) ? ((const float4*)user_emb)[i]
                                  : ((const float4*)item_emb)[i - USER_FLOAT4S];
    ((float4*)emb)[i] = v;
    ((float4*)acc)[i] = v;
    ((float4*)nxt)[i] = make_float4(0.f, 0.f, 0.f, 0.f);
}

__global__ void spmm_atomic_kernel(const int* __restrict__ rows,
                                   const int* __restrict__ cols,
                                   const float* __restrict__ vals,
                                   const float* __restrict__ x,
                                   float* __restrict__ y) {
    unsigned tid = blockIdx.x * blockDim.x + threadIdx.x;
    unsigned e  = tid >> 4;
    unsigned d4 = tid & 15u;
    if (e >= N_EDGES) return;
    int r = rows[e]; int c = cols[e]; float v = vals[e];
    float4 xv = ((const float4*)(x + (size_t)c * EMB_DIM))[d4];
    float* yp = y + (size_t)r * EMB_DIM + d4 * 4;
    atomicAdd(yp + 0, v * xv.x);
    atomicAdd(yp + 1, v * xv.y);
    atomicAdd(yp + 2, v * xv.z);
    atomicAdd(yp + 3, v * xv.w);
}

__global__ void acc_kernel(float* __restrict__ acc, const float* __restrict__ nxt,
                           float* __restrict__ zbuf, int do_zero, float scale) {
    int i = blockIdx.x * blockDim.x + threadIdx.x;
    if (i >= NODE_FLOAT4S) return;
    float4 a = ((float4*)acc)[i];
    float4 n = ((const float4*)nxt)[i];
    a.x = (a.x + n.x) * scale; a.y = (a.y + n.y) * scale;
    a.z = (a.z + n.z) * scale; a.w = (a.w + n.w) * scale;
    ((float4*)acc)[i] = a;
    if (do_zero) ((float4*)zbuf)[i] = make_float4(0.f, 0.f, 0.f, 0.f);
}

extern "C" void kernel_launch(void* const* d_in, const int* in_sizes, int n_in,
                              void* d_out, int out_size, void* d_ws, size_t ws_size,
                              hipStream_t stream) {
    const int*   rows     = (const int*)d_in[0];
    const int*   cols     = (const int*)d_in[1];
    const float* vals     = (const float*)d_in[2];
    const float* user_emb = (const float*)d_in[3];
    const float* item_emb = (const float*)d_in[4];
    float* out = (float*)d_out;

    // ws layout (u32 units):
    //   buf0 bf16 [4.8M]
    //   | STAGE region [9.6M]: stage_key [6.00064M] + stage_val u16 [3.00032M u32]
    //       (after stageB2 the region is dead; buf1 = [0..4.8M), buf2 = [4.8M..9.6M))
    //   | csr_col [6.0M padded] | csr_val u16 [3.0M u32] | desc [150K]
    //   | bx_pos [4688*16] | csr_cursor [16]
    constexpr size_t U_BUF   = (size_t)NODE_FLOATS / 2;   // 4,800,000
    constexpr size_t U_SKEY  = (size_t)SEG * CAP1;        // 6,000,640
    constexpr size_t U_STAGE = 2 * U_BUF;                 // 9,600,000 (>= U_SKEY+U_SVAL)
    constexpr size_t U_CCOL  = (size_t)CSR_CAP;           // 6,000,000
    constexpr size_t U_CVAL  = (size_t)CSR_CAP / 2;       // 3,000,000
    size_t need_u32 = U_BUF + U_STAGE + U_CCOL + U_CVAL + (size_t)N_NODES
                    + (size_t)SEG * 16 + 16;

    const int EW_BLOCKS = (NODE_FLOAT4S + 255) / 256;

    if (ws_size >= need_u32 * 4) {
        u32* W = (u32*)d_ws;
        u16* buf0      = (u16*)W;
        u32* stage_key = W + U_BUF;
        u16* stage_val = (u16*)(W + U_BUF + U_SKEY);
        u16* buf1      = (u16*)(W + U_BUF);               // alias: stage [0..4.8M)
        u16* buf2      = (u16*)(W + U_BUF + U_BUF);       // alias: stage [4.8M..9.6M)
        u32* csr_col   = W + U_BUF + U_STAGE;
        u16* csr_val   = (u16*)(csr_col + U_CCOL);
        u32* desc      = (u32*)(csr_col + U_CCOL + U_CVAL);
        int* bx_pos    = (int*)(desc + N_NODES);
        int* csr_cur   = bx_pos + (size_t)SEG * 16;

        init_ptrs_kernel<<<(SEG + 255) / 256, 256, 0, stream>>>(bx_pos, csr_cur);
        init_kernel<<<EW_BLOCKS, 256, 0, stream>>>(user_emb, item_emb, buf0);
        stageA2_kernel<<<ABLK2, 256, 0, stream>>>(rows, cols, vals, bx_pos,
                                                  stage_key, stage_val);
        stageB2_kernel<<<NB, 256, 0, stream>>>(bx_pos, stage_key, stage_val,
                                               csr_cur, csr_col, csr_val, desc);

        const int SPMM_BLOCKS = (N_NODES + 3) / 4;        // 4 rows (waves) per block
        spmm_rw_kernel<<<SPMM_BLOCKS, 256, 0, stream>>>(desc, csr_col, csr_val,
                                                        buf0, buf1, nullptr, nullptr, nullptr, nullptr);
        spmm_rw_kernel<<<SPMM_BLOCKS, 256, 0, stream>>>(desc, csr_col, csr_val,
                                                        buf1, buf2, nullptr, nullptr, nullptr, nullptr);
        spmm_rw_kernel<<<SPMM_BLOCKS, 256, 0, stream>>>(desc, csr_col, csr_val,
                                                        buf2, nullptr, buf0, buf1, buf2, out);
    } else {
        // fallback: R0 atomic path
        float* buf0 = (float*)d_ws;
        float* buf1 = buf0 + NODE_FLOATS;
        const int SPMM_BLOCKS = (int)(((size_t)N_EDGES * 16 + 255) / 256);
        init3_kernel<<<EW_BLOCKS, 256, 0, stream>>>(user_emb, item_emb, buf0, out, buf1);
        float* prev = buf0; float* next = buf1;
        for (int layer = 0; layer < 3; ++layer) {
            spmm_atomic_kernel<<<SPMM_BLOCKS, 256, 0, stream>>>(rows, cols, vals, prev, next);
            if (layer < 2) acc_kernel<<<EW_BLOCKS, 256, 0, stream>>>(out, next, prev, 1, 1.0f);
            else           acc_kernel<<<EW_BLOCKS, 256, 0, stream>>>(out, next, prev, 0, 0.25f);
            float* t = prev; prev = next; next = t;
        }
    }
}

// Round 5
// 490.701 us; speedup vs baseline: 1.9996x; 1.0166x over previous
//
#include <hip/hip_runtime.h>

// LightGCN: out = (e0 + A e0 + A^2 e0 + A^3 e0) / 4 over 150K nodes, 4.8M COO edges, D=64.
// R11: spmm reverted to R8's plain row-per-wave kernel (best measured 91.4us;
// R8/R9/R10 proved the gather loop is pinned at ~3.9 TB/s L2-miss throughput --
// a memory-side ceiling, not issue-side). This round attacks the ~215us of
// NON-spmm time: (a) buckets halved to 128 rows -> stageB2 1172 blocks x 38KB LDS
// = 4 blocks/CU (was 586 x 66KB = 2/CU, latency-exposed); (b) init_ptrs + e0->bf16
// fused into one prelude kernel (7 -> 6 launches). CSR padding + ws aliasing kept.

#define N_USERS 100000
#define N_ITEMS 50000
#define N_NODES 150000
#define N_EDGES 4800000
#define EMB_DIM 64

typedef unsigned short u16;
typedef unsigned int   u32;

constexpr int NODE_FLOATS  = N_NODES * EMB_DIM;      // 9,600,000
constexpr int NODE_FLOAT4S = NODE_FLOATS / 4;        // 2,400,000
constexpr int USER_FLOAT4S = N_USERS * EMB_DIM / 4;  // 1,600,000

constexpr int BSH  = 7;                              // bucket shift (128 rows)
constexpr int BRW  = 128;                            // rows per bucket
constexpr int NB   = (N_NODES + BRW - 1) / BRW;      // 1172 buckets
constexpr int NXG  = 8;                              // XCD groups (blockIdx & 7)
constexpr int SEG  = NB * NXG;                       // 9376 (bucket,x) segments
constexpr int CAP1 = 704;                            // per-segment cap (mean 512, +8.5 sigma)
constexpr int EPB  = 6144;                           // edges per stageA2 block
constexpr int ABLK2 = (N_EDGES + EPB - 1) / EPB;     // 782
constexpr int SB_CAP2 = 5760;                        // stageB2 LDS records, PADDED (mean 5082, +8 sigma)
constexpr int CSR_CAP = 6000000;                     // padded CSR entries (mean 5.95M, +16 sigma)

// ---- bf16 helpers (RNE) ----
static __device__ __forceinline__ float bf2f(u16 b) {
    return __uint_as_float(((u32)b) << 16);
}
static __device__ __forceinline__ u16 f2bf(float f) {
    u32 u = __float_as_uint(f);
    return (u16)((u + 0x7FFFu + ((u >> 16) & 1u)) >> 16);
}

// ---------------- prelude: buf0 = bf16(e0), init segment frontiers ----------------
__global__ void prelude_kernel(const float* __restrict__ user_emb,
                               const float* __restrict__ item_emb,
                               u16* __restrict__ emb,
                               int* __restrict__ bx_pos,
                               int* __restrict__ csr_cursor) {
    int i = blockIdx.x * blockDim.x + threadIdx.x;
    if (i < SEG) bx_pos[i * 16] = i * CAP1;
    if (i == 0) csr_cursor[0] = 0;
    if (i >= NODE_FLOAT4S) return;
    float4 v = (i < USER_FLOAT4S) ? ((const float4*)user_emb)[i]
                                  : ((const float4*)item_emb)[i - USER_FLOAT4S];
    ushort4 o;
    o.x = f2bf(v.x); o.y = f2bf(v.y); o.z = f2bf(v.z); o.w = f2bf(v.w);
    ((ushort4*)emb)[i] = o;
}

// ---------------- stage A2: block-local counting sort by bucket ----------------
__global__ void stageA2_kernel(const int* __restrict__ rows,
                               const int* __restrict__ cols,
                               const float* __restrict__ vals,
                               int* __restrict__ bx_pos,
                               u32* __restrict__ stage_key,
                               u16* __restrict__ stage_val) {
    __shared__ u32 lkey[EPB];          // 24 KB
    __shared__ u16 lval[EPB];          // 12 KB
    __shared__ u16 lbkt[EPB];          // 12 KB
    __shared__ int hist[NB];           // 4.7 KB x4 = 18.75 KB
    __shared__ int hstart[NB];
    __shared__ int hcur[NB];
    __shared__ int gbase[NB];
    __shared__ int ws4[4];

    const int tid  = threadIdx.x;
    const int base = blockIdx.x * EPB;
    const int cnt  = min(EPB, N_EDGES - base);
    const int x    = blockIdx.x & (NXG - 1);

    for (int i = tid; i < NB; i += 256) hist[i] = 0;
    __syncthreads();

    for (int k = 0; k < EPB / 256; k += 8) {
        int rbuf[8];
        #pragma unroll
        for (int q = 0; q < 8; ++q) {
            int idx = (k + q) * 256 + tid;
            rbuf[q] = (idx < cnt) ? rows[base + idx] : -1;
        }
        #pragma unroll
        for (int q = 0; q < 8; ++q)
            if (rbuf[q] >= 0) atomicAdd(&hist[rbuf[q] >> BSH], 1);
    }
    __syncthreads();

    const int lane = tid & 63, wave = tid >> 6;
    int carry = 0;
    for (int c0 = 0; c0 < NB; c0 += 256) {
        int i = c0 + tid;
        int v = (i < NB) ? hist[i] : 0;
        int incl = v;
        #pragma unroll
        for (int off = 1; off < 64; off <<= 1) {
            int t = __shfl_up(incl, off);
            if (lane >= off) incl += t;
        }
        if (lane == 63) ws4[wave] = incl;
        __syncthreads();
        int wpref = 0, tot = 0;
        #pragma unroll
        for (int w = 0; w < 4; ++w) { int s = ws4[w]; if (w < wave) wpref += s; tot += s; }
        int excl = carry + wpref + incl - v;
        if (i < NB) { hstart[i] = excl; hcur[i] = excl; }
        carry += tot;
        __syncthreads();
    }

    for (int k = 0; k < EPB / 256; k += 8) {
        int rb[8], cb[8]; float vb[8];
        #pragma unroll
        for (int q = 0; q < 8; ++q) {
            int idx = (k + q) * 256 + tid;
            if (idx < cnt) { rb[q] = rows[base + idx]; cb[q] = cols[base + idx]; vb[q] = vals[base + idx]; }
            else rb[q] = -1;
        }
        #pragma unroll
        for (int q = 0; q < 8; ++q) {
            if (rb[q] < 0) continue;
            int b = rb[q] >> BSH;
            int p = atomicAdd(&hcur[b], 1);
            lkey[p] = ((u32)(rb[q] & (BRW - 1)) << 24) | (u32)cb[q];
            lval[p] = f2bf(vb[q]);
            lbkt[p] = (u16)b;
        }
    }
    __syncthreads();

    for (int i = tid; i < NB; i += 256) {
        int n = hist[i];
        if (n) {
            int seg = i * NXG + x;
            int p = atomicAdd(&bx_pos[seg * 16], n);
            gbase[i] = (p + n <= (seg + 1) * CAP1) ? p : -1;
        }
    }
    __syncthreads();

    for (int i = tid; i < cnt; i += 256) {
        int b  = lbkt[i];
        int gb = gbase[b];
        if (gb >= 0) {
            int d = gb + (i - hstart[b]);
            stage_key[d] = lkey[i];
            stage_val[d] = lval[i];
        }
    }
}

// -------- stage B2: per-bucket row sort in LDS, 16-PADDED contiguous CSR --------
// 128-row buckets -> 1172 blocks x ~38 KB LDS = 4 blocks/CU (2x the TLP of R10's
// 586 x 66 KB). Each row's segment padded to a multiple of 16 with (col=0,val=0)
// dummies so spmm has no remainder path. desc[row] = (abs_beg << 8) | padded_cnt.
__global__ void stageB2_kernel(const int* __restrict__ bx_pos,
                               const u32* __restrict__ stage_key,
                               const u16* __restrict__ stage_val,
                               int* __restrict__ csr_cursor,
                               u32* __restrict__ csr_col,
                               u16* __restrict__ csr_val,
                               u32* __restrict__ desc) {
    __shared__ u32 skey[SB_CAP2];      // 23 KB (col only)
    __shared__ u16 sval[SB_CAP2];      // 11.5 KB
    __shared__ int rhist[256], rpad0[256], rcur[256];   // bins 0..127 used
    __shared__ int ws4[4];
    __shared__ int sbase_sh;

    const int b   = blockIdx.x;
    const int tid = threadIdx.x;
    rhist[tid] = 0;
    __syncthreads();

    for (int xx = 0; xx < NXG; ++xx) {
        int seg = b * NXG + xx;
        int sb  = seg * CAP1;
        int n   = min(bx_pos[seg * 16] - sb, CAP1);
        for (int i = tid; i < n; i += 256)
            atomicAdd(&rhist[stage_key[sb + i] >> 24], 1);
    }
    __syncthreads();

    const int lane = tid & 63, wave = tid >> 6;
    int v  = rhist[tid];
    int vp = (v + 15) & ~15;           // padded count (zero for unused bins 128..255)
    int incl = vp;
    #pragma unroll
    for (int off = 1; off < 64; off <<= 1) {
        int t = __shfl_up(incl, off);
        if (lane >= off) incl += t;
    }
    if (lane == 63) ws4[wave] = incl;
    __syncthreads();
    int wpref = 0, total = 0;
    #pragma unroll
    for (int w = 0; w < 4; ++w) { int s = ws4[w]; if (w < wave) wpref += s; total += s; }
    int excl = wpref + incl - vp;
    rpad0[tid] = excl;
    rcur[tid]  = excl;
    if (tid == 0) sbase_sh = atomicAdd(csr_cursor, total);
    __syncthreads();

    const int tcap = min(total, SB_CAP2);
    // pre-fill with dummies (col 0, val 0) -> padded slots contribute 0 in spmm
    for (int i = tid; i < tcap; i += 256) { skey[i] = 0u; sval[i] = 0; }
    __syncthreads();

    for (int xx = 0; xx < NXG; ++xx) {
        int seg = b * NXG + xx;
        int sb  = seg * CAP1;
        int n   = min(bx_pos[seg * 16] - sb, CAP1);
        for (int i = tid; i < n; i += 256) {
            u32 key = stage_key[sb + i];
            u16 val = stage_val[sb + i];
            int p = atomicAdd(&rcur[key >> 24], 1);
            if (p < SB_CAP2) { skey[p] = key & 0x00FFFFFFu; sval[p] = val; }
        }
    }
    __syncthreads();

    const int sbase = sbase_sh;
    for (int i = tid; i < tcap; i += 256) {
        int g = sbase + i;
        if (g < CSR_CAP) { csr_col[g] = skey[i]; csr_val[g] = sval[i]; }
    }
    if (tid < BRW) {
        int grow = b * BRW + tid;
        if (grow < N_NODES) {
            int cp = vp; if (cp > 240) cp = 240;
            desc[grow] = ((u32)(sbase + rpad0[tid]) << 8) | (u32)cp;
        }
    }
}

// ------- CSR SpMM: ONE ROW PER WAVE (64 lanes = 64 embedding elements) -------
// R8's kernel verbatim (best measured: 91.4us/dispatch, occ 75%). The gather loop
// is pinned at ~3.9 TB/s L2-miss-path throughput (R8/R9/R10 invariance) -- the
// pattern's memory-side ceiling. Do not re-optimize issue-side.
// layers 1/2: y = A x (bf16). layer 3 (y==null): out = (e0 + y1 + y2 + A x)/4 fp32.
__global__ __launch_bounds__(256, 8)
void spmm_rw_kernel(const u32* __restrict__ desc,
                    const u32* __restrict__ csr_col,
                    const u16* __restrict__ csr_val,
                    const u16* __restrict__ x,
                    u16* __restrict__ y,
                    const u16* __restrict__ e0,
                    const u16* __restrict__ y1,
                    const u16* __restrict__ y2,
                    float* __restrict__ out) {
    const int lane = threadIdx.x & 63;
    const int wid  = __builtin_amdgcn_readfirstlane(threadIdx.x >> 6);
    const int row  = blockIdx.x * 4 + wid;
    if (row >= N_NODES) return;

    const u32 d   = desc[row];
    const int beg = (int)(d >> 8);
    const int nch = (int)(d & 255u) >> 4;

    const u32* __restrict__ pc = csr_col + beg;
    const u32* __restrict__ pv = ((const u32*)csr_val) + (beg >> 1);  // beg even (16-aligned)
    const u16* __restrict__ xl = x + lane;

    float a[4] = {0.f, 0.f, 0.f, 0.f};

    for (int ch = 0; ch < nch; ++ch) {
        u32 c[16];
        u32 w[8];
        #pragma unroll
        for (int k = 0; k < 16; ++k) c[k] = pc[ch * 16 + k];   // scalar (s_load) stream
        #pragma unroll
        for (int k = 0; k < 8; ++k)  w[k] = pv[ch * 8 + k];    // scalar bf16 vals x2

        u32 xv[16];
        #pragma unroll
        for (int k = 0; k < 16; ++k)
            xv[k] = (u32)xl[(size_t)c[k] * EMB_DIM];           // 16 independent 1-VGPR gathers

        #pragma unroll
        for (int k = 0; k < 16; ++k) {
            u32 vb = (k & 1) ? (w[k >> 1] & 0xFFFF0000u) : (w[k >> 1] << 16);
            float vv = __uint_as_float(vb);
            float xf = __uint_as_float(xv[k] << 16);
            a[k & 3] += vv * xf;
        }
    }
    float s = (a[0] + a[1]) + (a[2] + a[3]);

    size_t oidx = (size_t)row * EMB_DIM + lane;
    if (y) {
        y[oidx] = f2bf(s);
    } else {
        float r = (bf2f(e0[oidx]) + bf2f(y1[oidx]) + bf2f(y2[oidx]) + s) * 0.25f;
        out[oidx] = r;
    }
}

// ---------------- fallback (R0 atomic path) ----------------
__global__ void init3_kernel(const float* __restrict__ user_emb,
                             const float* __restrict__ item_emb,
                             float* __restrict__ emb,
                             float* __restrict__ acc,
                             float* __restrict__ nxt) {
    int i = blockIdx.x * blockDim.x + threadIdx.x;
    if (i >= NODE_FLOAT4S) return;
    float4 v = (i < USER_FLOAT4S) ? ((const float4*)user_emb)[i]
                                  : ((const float4*)item_emb)[i - USER_FLOAT4S];
    ((float4*)emb)[i] = v;
    ((float4*)acc)[i] = v;
    ((float4*)nxt)[i] = make_float4(0.f, 0.f, 0.f, 0.f);
}

__global__ void spmm_atomic_kernel(const int* __restrict__ rows,
                                   const int* __restrict__ cols,
                                   const float* __restrict__ vals,
                                   const float* __restrict__ x,
                                   float* __restrict__ y) {
    unsigned tid = blockIdx.x * blockDim.x + threadIdx.x;
    unsigned e  = tid >> 4;
    unsigned d4 = tid & 15u;
    if (e >= N_EDGES) return;
    int r = rows[e]; int c = cols[e]; float v = vals[e];
    float4 xv = ((const float4*)(x + (size_t)c * EMB_DIM))[d4];
    float* yp = y + (size_t)r * EMB_DIM + d4 * 4;
    atomicAdd(yp + 0, v * xv.x);
    atomicAdd(yp + 1, v * xv.y);
    atomicAdd(yp + 2, v * xv.z);
    atomicAdd(yp + 3, v * xv.w);
}

__global__ void acc_kernel(float* __restrict__ acc, const float* __restrict__ nxt,
                           float* __restrict__ zbuf, int do_zero, float scale) {
    int i = blockIdx.x * blockDim.x + threadIdx.x;
    if (i >= NODE_FLOAT4S) return;
    float4 a = ((float4*)acc)[i];
    float4 n = ((const float4*)nxt)[i];
    a.x = (a.x + n.x) * scale; a.y = (a.y + n.y) * scale;
    a.z = (a.z + n.z) * scale; a.w = (a.w + n.w) * scale;
    ((float4*)acc)[i] = a;
    if (do_zero) ((float4*)zbuf)[i] = make_float4(0.f, 0.f, 0.f, 0.f);
}

extern "C" void kernel_launch(void* const* d_in, const int* in_sizes, int n_in,
                              void* d_out, int out_size, void* d_ws, size_t ws_size,
                              hipStream_t stream) {
    const int*   rows     = (const int*)d_in[0];
    const int*   cols     = (const int*)d_in[1];
    const float* vals     = (const float*)d_in[2];
    const float* user_emb = (const float*)d_in[3];
    const float* item_emb = (const float*)d_in[4];
    float* out = (float*)d_out;

    // ws layout (u32 units):
    //   buf0 bf16 [4.8M]
    //   | STAGE region [9.9M]: stage_key [6.6M] + stage_val u16 [3.3M u32]
    //       (after stageB2 the region is dead; buf1 = [0..4.8M), buf2 = [4.8M..9.6M))
    //   | csr_col [6.0M padded] | csr_val u16 [3.0M u32] | desc [150K]
    //   | bx_pos [9376*16] | csr_cursor [16]
    constexpr size_t U_BUF   = (size_t)NODE_FLOATS / 2;   // 4,800,000
    constexpr size_t U_SKEY  = (size_t)SEG * CAP1;        // 6,600,704
    constexpr size_t U_SVAL  = U_SKEY / 2;                // 3,300,352
    constexpr size_t U_STAGE = U_SKEY + U_SVAL;           // 9,901,056 (>= 9.6M for buf1+buf2)
    constexpr size_t U_CCOL  = (size_t)CSR_CAP;           // 6,000,000
    constexpr size_t U_CVAL  = (size_t)CSR_CAP / 2;       // 3,000,000
    size_t need_u32 = U_BUF + U_STAGE + U_CCOL + U_CVAL + (size_t)N_NODES
                    + (size_t)SEG * 16 + 16;

    const int EW_BLOCKS = (NODE_FLOAT4S + 255) / 256;

    if (ws_size >= need_u32 * 4) {
        u32* W = (u32*)d_ws;
        u16* buf0      = (u16*)W;
        u32* stage_key = W + U_BUF;
        u16* stage_val = (u16*)(W + U_BUF + U_SKEY);
        u16* buf1      = (u16*)(W + U_BUF);               // alias: stage [0..4.8M)
        u16* buf2      = (u16*)(W + U_BUF + U_BUF);       // alias: stage [4.8M..9.6M)
        u32* csr_col   = W + U_BUF + U_STAGE;
        u16* csr_val   = (u16*)(csr_col + U_CCOL);
        u32* desc      = (u32*)(csr_col + U_CCOL + U_CVAL);
        int* bx_pos    = (int*)(desc + N_NODES);
        int* csr_cur   = bx_pos + (size_t)SEG * 16;

        prelude_kernel<<<EW_BLOCKS, 256, 0, stream>>>(user_emb, item_emb, buf0,
                                                      bx_pos, csr_cur);
        stageA2_kernel<<<ABLK2, 256, 0, stream>>>(rows, cols, vals, bx_pos,
                                                  stage_key, stage_val);
        stageB2_kernel<<<NB, 256, 0, stream>>>(bx_pos, stage_key, stage_val,
                                               csr_cur, csr_col, csr_val, desc);

        const int SPMM_BLOCKS = (N_NODES + 3) / 4;        // 4 rows (waves) per block
        spmm_rw_kernel<<<SPMM_BLOCKS, 256, 0, stream>>>(desc, csr_col, csr_val,
                                                        buf0, buf1, nullptr, nullptr, nullptr, nullptr);
        spmm_rw_kernel<<<SPMM_BLOCKS, 256, 0, stream>>>(desc, csr_col, csr_val,
                                                        buf1, buf2, nullptr, nullptr, nullptr, nullptr);
        spmm_rw_kernel<<<SPMM_BLOCKS, 256, 0, stream>>>(desc, csr_col, csr_val,
                                                        buf2, nullptr, buf0, buf1, buf2, out);
    } else {
        // fallback: R0 atomic path
        float* buf0 = (float*)d_ws;
        float* buf1 = buf0 + NODE_FLOATS;
        const int SPMM_BLOCKS = (int)(((size_t)N_EDGES * 16 + 255) / 256);
        init3_kernel<<<EW_BLOCKS, 256, 0, stream>>>(user_emb, item_emb, buf0, out, buf1);
        float* prev = buf0; float* next = buf1;
        for (int layer = 0; layer < 3; ++layer) {
            spmm_atomic_kernel<<<SPMM_BLOCKS, 256, 0, stream>>>(rows, cols, vals, prev, next);
            if (layer < 2) acc_kernel<<<EW_BLOCKS, 256, 0, stream>>>(out, next, prev, 1, 1.0f);
            else           acc_kernel<<<EW_BLOCKS, 256, 0, stream>>>(out, next, prev, 0, 0.25f);
            float* t = prev; prev = next; next = t;
        }
    }
}